// Round 12
// baseline (154.630 us; speedup 1.0000x reference)
//
#include <hip/hip_runtime.h>

#define Bn 4
#define Qn 1024
#define Kn 1024
#define Dd 256
#define Hh 64
#define Dv 256
#define TQ 16

typedef __attribute__((ext_vector_type(8))) short short8;
typedef __attribute__((ext_vector_type(4))) float floatx4;

__device__ __forceinline__ short f32_to_bf16(float x) {
    unsigned u = __float_as_uint(x);
    unsigned r = u + 0x7fffu + ((u >> 16) & 1u);   // RNE
    return (short)(r >> 16);
}
__device__ __forceinline__ float bf16_to_f32(short h) {
    return __uint_as_float(((unsigned)(unsigned short)h) << 16);
}

// Fused prep:
//  blocks 0..255  : q-projection (Eq, exp-folded), coalesced stores
//  blocks 256..319: k-projection -> LDS transpose -> COALESCED Ekt stores
//                   (old path scattered 64 lanes across 64 cache lines per
//                   store instr — 4B useful/line on 1MB of stores)
//  blocks 320..447: V -> split-bf16 MFMA-A-fragment swizzle
__global__ __launch_bounds__(256) void prep_kernel(const float* __restrict__ Xq,
                                                   const float* __restrict__ Wq,
                                                   const float* __restrict__ Xk,
                                                   const float* __restrict__ Wk,
                                                   const float* __restrict__ V,
                                                   float* __restrict__ Eq,
                                                   float* __restrict__ Ekt,
                                                   short* __restrict__ Vhi,
                                                   short* __restrict__ Vlo) {
    __shared__ float tile[32 * 261];              // 33.4 KB, unioned use
    int t = threadIdx.x;
    if (blockIdx.x < 256) {
        // ---- q-projection: 4 rows per wave ----
        int gw = blockIdx.x * 4 + (t >> 6);       // 0..1023
        int h = t & 63;
        int row0 = gw * 4;
        float acc[4] = {0.f, 0.f, 0.f, 0.f};
        for (int d4 = 0; d4 < Dd / 4; ++d4) {
            float w0 = Wq[(d4 * 4 + 0) * Hh + h];
            float w1 = Wq[(d4 * 4 + 1) * Hh + h];
            float w2 = Wq[(d4 * 4 + 2) * Hh + h];
            float w3 = Wq[(d4 * 4 + 3) * Hh + h];
            #pragma unroll
            for (int r = 0; r < 4; ++r) {
                float4 xv = ((const float4*)(Xq + (row0 + r) * Dd))[d4]; // uniform
                acc[r] = fmaf(xv.x, w0, acc[r]);
                acc[r] = fmaf(xv.y, w1, acc[r]);
                acc[r] = fmaf(xv.z, w2, acc[r]);
                acc[r] = fmaf(xv.w, w3, acc[r]);
            }
        }
        #pragma unroll
        for (int r = 0; r < 4; ++r)
            Eq[(row0 + r) * Hh + h] = __expf(2.f * acc[r]);   // coalesced
    } else if (blockIdx.x < 320) {
        // ---- k-projection, 64 rows/block, transposed store via LDS ----
        int blkk = blockIdx.x - 256;               // 0..63
        int b = blkk >> 4, k0 = (blkk & 15) * 64;
        const float* X = Xk + ((size_t)b * Kn + k0) * Dd;
        int wv_ = t >> 6, h = t & 63;
        float acc[16];
        #pragma unroll
        for (int r = 0; r < 16; ++r) acc[r] = 0.f;
        for (int d4 = 0; d4 < Dd / 4; ++d4) {
            float w0 = Wk[(d4 * 4 + 0) * Hh + h];
            float w1 = Wk[(d4 * 4 + 1) * Hh + h];
            float w2 = Wk[(d4 * 4 + 2) * Hh + h];
            float w3 = Wk[(d4 * 4 + 3) * Hh + h];
            #pragma unroll
            for (int r = 0; r < 16; ++r) {
                float4 xv = ((const float4*)(X + (wv_ * 16 + r) * Dd))[d4]; // uniform
                acc[r] = fmaf(xv.x, w0, acc[r]);
                acc[r] = fmaf(xv.y, w1, acc[r]);
                acc[r] = fmaf(xv.z, w2, acc[r]);
                acc[r] = fmaf(xv.w, w3, acc[r]);
            }
        }
        // LDS transpose: tile[h][k_local], stride 65 -> (h+c)%32 banks, free
        #pragma unroll
        for (int r = 0; r < 16; ++r)
            tile[h * 65 + wv_ * 16 + r] = __expf(2.f * acc[r]);
        __syncthreads();
        // coalesced store: lane = k, 256B contiguous per instruction
        for (int i = 0; i < 16; ++i) {
            int ho = wv_ * 16 + i;
            Ekt[((size_t)b * Hh + ho) * Kn + k0 + h] = tile[ho * 65 + h];
        }
    } else {
        // ---- V prep: swizzle into MFMA A-fragment order, hi+lo bf16 ----
        int blk = blockIdx.x - 320;
        int b = blk >> 5;
        int kt = blk & 31;
        const float* Vg = V + (b * Kn + kt * 32) * Dv;
        for (int i = 0; i < 8; ++i) {
            int k = i * 4 + (t >> 6);
            int n4 = (t & 63) * 4;
            float4 v = *(const float4*)(Vg + k * Dv + n4);
            tile[k * 261 + n4 + 0] = v.x;
            tile[k * 261 + n4 + 1] = v.y;
            tile[k * 261 + n4 + 2] = v.z;
            tile[k * 261 + n4 + 3] = v.w;
        }
        __syncthreads();
        int wave = t >> 6, l = t & 63;
        int n_in = l & 15, kc = l >> 4;
        for (int p = 0; p < 4; ++p) {
            int nt = wave * 4 + p;
            int n = nt * 16 + n_in;
            short8 hi, lo;
            #pragma unroll
            for (int j = 0; j < 8; ++j) {
                float x = tile[(kc * 8 + j) * 261 + n];
                short hs = f32_to_bf16(x);
                hi[j] = hs;
                lo[j] = f32_to_bf16(x - bf16_to_f32(hs));
            }
            size_t base = (((size_t)(b * 32 + kt) * 16 + nt) * 512) + (size_t)l * 8;
            *(short8*)(Vhi + base) = hi;
            *(short8*)(Vlo + base) = lo;
        }
    }
}

// score(q,k) = W_sum - 2*sum_h w_h/(Eq_h*Ek_h+1); W_sum cancels in softmax.
// Bounded scores -> no max-subtraction; p = exp(-2s) fused into score phase.
// R12: thread's 64 Ekt values preloaded ONCE into VGPRs (R11 re-streamed them
// 16x and stalled on in-loop s_loads at VGPR=24); q-outer loop, h4 unrolled,
// qv/w4 via batched s_loads hidden under ~640 VALU cyc per q-iteration.
__global__ __launch_bounds__(1024, 4) void attn_kernel(const float* __restrict__ Eq,
                                                       const float* __restrict__ Ekt,
                                                       const short* __restrict__ Vhi,
                                                       const short* __restrict__ Vlo,
                                                       const float* __restrict__ wv,
                                                       float* __restrict__ out) {
    __shared__ __align__(16) unsigned sc[TQ * 1028];   // 65.8 KB: P hi/lo shorts
    __shared__ float wsum[16 * TQ];
    __shared__ float rinv_s[TQ];

    int tid = threadIdx.x;
    int blk = blockIdx.x;
    // XCD swizzle: blk%8 = XCD; batch b pinned to XCDs {2b,2b+1}.
    int b = (blk & 7) >> 1;
    int tile = (blk >> 3) * 2 + (blk & 1);   // 0..63, bijective per batch
    int qbase = tile * TQ;

    // ---- preload this thread's 64 Ek values (coalesced dword loads) ----
    const float* kb = Ekt + (size_t)b * Hh * Kn + tid;
    float e[Hh];
    #pragma unroll
    for (int h = 0; h < Hh; ++h) e[h] = kb[(size_t)h * Kn];

    // ---- score phase: q outer, h4 inner unrolled ----
    const float* qp = Eq + (size_t)(b * Qn + qbase) * Hh;
    const float4* wv4 = (const float4*)wv;
    unsigned short* sp = (unsigned short*)sc;
    float part[TQ];
    for (int q = 0; q < TQ; ++q) {
        const float4* qr = (const float4*)(qp + q * Hh);   // wave-uniform
        float s = 0.f;
        #pragma unroll
        for (int h4 = 0; h4 < Hh / 4; ++h4) {
            float4 qv = qr[h4];                            // s_load_dwordx4
            float4 w4 = wv4[h4];                           // s_load (hoistable)
            float a  = fmaf(qv.x, e[4 * h4 + 0], 1.f);
            float bb = fmaf(qv.y, e[4 * h4 + 1], 1.f);
            float c  = fmaf(qv.z, e[4 * h4 + 2], 1.f);
            float d  = fmaf(qv.w, e[4 * h4 + 3], 1.f);
            float nab = fmaf(w4.x, bb, w4.y * a);
            float ncd = fmaf(w4.z, d, w4.w * c);
            s = fmaf(nab, __builtin_amdgcn_rcpf(a * bb), s);
            s = fmaf(ncd, __builtin_amdgcn_rcpf(c * d), s);
        }
        float p = __expf(-2.f * s);
        part[q] = p;
        short hs = f32_to_bf16(p);
        sp[q * 2056 + tid] = (unsigned short)hs;
        sp[q * 2056 + 1024 + tid] = (unsigned short)f32_to_bf16(p - bf16_to_f32(hs));
    }

    int wave = tid >> 6, lane = tid & 63;
    #pragma unroll
    for (int q = 0; q < TQ; ++q) {
        #pragma unroll
        for (int off = 32; off >= 1; off >>= 1)
            part[q] += __shfl_xor(part[q], off, 64);
    }
    if (lane == 0) {
        #pragma unroll
        for (int q = 0; q < TQ; ++q) wsum[wave * TQ + q] = part[q];
    }
    __syncthreads();

    {   // wave w finalizes row q=w: sum 16 per-wave partials
        float v = (lane < 16) ? wsum[lane * TQ + wave] : 0.f;
        v += __shfl_xor(v, 8, 64);
        v += __shfl_xor(v, 4, 64);
        v += __shfl_xor(v, 2, 64);
        v += __shfl_xor(v, 1, 64);
        if (lane == 0) rinv_s[wave] = 1.f / v;
    }
    __syncthreads();

    // ---- AV via MFMA: wave owns ntile = wave; all 16 q-cols live ----
    int qf = lane & 15, kc = lane >> 4;
    floatx4 acc = {0.f, 0.f, 0.f, 0.f};
    const char* scb = (const char*)sc;
    for (int kt = 0; kt < 32; ++kt) {
        short8 bhi = *(const short8*)(scb + qf * 4112 + kt * 64 + kc * 16);
        short8 blo = *(const short8*)(scb + qf * 4112 + 2048 + kt * 64 + kc * 16);
        size_t base = (((size_t)(b * 32 + kt) * 16 + wave) * 512) + (size_t)lane * 8;
        short8 ah = *(const short8*)(Vhi + base);
        short8 al = *(const short8*)(Vlo + base);
        acc = __builtin_amdgcn_mfma_f32_16x16x32_bf16(ah, bhi, acc, 0, 0, 0);
        acc = __builtin_amdgcn_mfma_f32_16x16x32_bf16(al, bhi, acc, 0, 0, 0);
        acc = __builtin_amdgcn_mfma_f32_16x16x32_bf16(ah, blo, acc, 0, 0, 0);
    }
    {
        float r = rinv_s[qf];
        float* ob = out + ((size_t)(b * Qn + qbase + qf)) * Dv + wave * 16 + kc * 4;
        float4 o = { acc[0] * r, acc[1] * r, acc[2] * r, acc[3] * r };
        *(float4*)ob = o;
    }
}

extern "C" void kernel_launch(void* const* d_in, const int* in_sizes, int n_in,
                              void* d_out, int out_size, void* d_ws, size_t ws_size,
                              hipStream_t stream) {
    const float* queries = (const float*)d_in[0];
    const float* keys    = (const float*)d_in[1];
    const float* values  = (const float*)d_in[2];
    const float* W_q     = (const float*)d_in[3];
    const float* W_k     = (const float*)d_in[4];
    const float* w_v     = (const float*)d_in[5];
    float* out = (float*)d_out;

    float* Eq  = (float*)d_ws;                 // [B*Q, H]      1 MB
    float* Ekt = Eq + Bn * Qn * Hh;            // [B, H, K]     1 MB
    short* Vhi = (short*)(Ekt + Bn * Kn * Hh); // frag-order    2 MB
    short* Vlo = Vhi + (size_t)Bn * Kn * Dv;   // frag-order    2 MB

    prep_kernel<<<448, 256, 0, stream>>>(queries, W_q, keys, W_k, values,
                                         Eq, Ekt, Vhi, Vlo);
    attn_kernel<<<Bn * (Qn / TQ), 1024, 0, stream>>>(Eq, Ekt, Vhi, Vlo, w_v, out);
}

// Round 13
// 129.504 us; speedup vs baseline: 1.1940x; 1.1940x over previous
//
#include <hip/hip_runtime.h>

#define Bn 4
#define Qn 1024
#define Kn 1024
#define Dd 256
#define Hh 64
#define Dv 256
#define TQ 16

typedef __attribute__((ext_vector_type(8))) short short8;
typedef __attribute__((ext_vector_type(4))) float floatx4;

__device__ __forceinline__ short f32_to_bf16(float x) {
    unsigned u = __float_as_uint(x);
    unsigned r = u + 0x7fffu + ((u >> 16) & 1u);   // RNE
    return (short)(r >> 16);
}
__device__ __forceinline__ float bf16_to_f32(short h) {
    return __uint_as_float(((unsigned)(unsigned short)h) << 16);
}

// Fused prep (R11 exact — R12's k-proj "fix" regressed 20us by concentrating
// k-side work into 64 blocks of serialized wave-uniform X loads):
//  blocks 0..511  : projections (Eq + transposed Ekt, exp-folded), 4 rows/wave
//  blocks 512..639: V -> split-bf16 MFMA-A-fragment swizzle
__global__ __launch_bounds__(256) void prep_kernel(const float* __restrict__ Xq,
                                                   const float* __restrict__ Wq,
                                                   const float* __restrict__ Xk,
                                                   const float* __restrict__ Wk,
                                                   const float* __restrict__ V,
                                                   float* __restrict__ Eq,
                                                   float* __restrict__ Ekt,
                                                   short* __restrict__ Vhi,
                                                   short* __restrict__ Vlo) {
    __shared__ float tile[32 * 261];
    int t = threadIdx.x;
    if (blockIdx.x < 512) {
        int gw = blockIdx.x * 4 + (t >> 6);
        int h = t & 63;
        int side = gw >> 10;
        int row0 = (gw & 1023) * 4;
        const float* X = side ? Xk : Xq;
        const float* W = side ? Wk : Wq;
        float acc[4] = {0.f, 0.f, 0.f, 0.f};
        for (int d4 = 0; d4 < Dd / 4; ++d4) {
            float w0 = W[(d4 * 4 + 0) * Hh + h];
            float w1 = W[(d4 * 4 + 1) * Hh + h];
            float w2 = W[(d4 * 4 + 2) * Hh + h];
            float w3 = W[(d4 * 4 + 3) * Hh + h];
            #pragma unroll
            for (int r = 0; r < 4; ++r) {
                float4 xv = ((const float4*)(X + (row0 + r) * Dd))[d4];
                acc[r] = fmaf(xv.x, w0, acc[r]);
                acc[r] = fmaf(xv.y, w1, acc[r]);
                acc[r] = fmaf(xv.z, w2, acc[r]);
                acc[r] = fmaf(xv.w, w3, acc[r]);
            }
        }
        #pragma unroll
        for (int r = 0; r < 4; ++r) {
            int row = row0 + r;
            float e = __expf(2.f * acc[r]);
            if (!side) {
                Eq[row * Hh + h] = e;
            } else {
                int b = row >> 10, k = row & 1023;
                Ekt[(b * Hh + h) * Kn + k] = e;
            }
        }
    } else {
        int blk = blockIdx.x - 512;
        int b = blk >> 5;
        int kt = blk & 31;
        const float* Vg = V + (b * Kn + kt * 32) * Dv;
        for (int i = 0; i < 8; ++i) {
            int k = i * 4 + (t >> 6);
            int n4 = (t & 63) * 4;
            float4 v = *(const float4*)(Vg + k * Dv + n4);
            tile[k * 261 + n4 + 0] = v.x;
            tile[k * 261 + n4 + 1] = v.y;
            tile[k * 261 + n4 + 2] = v.z;
            tile[k * 261 + n4 + 3] = v.w;
        }
        __syncthreads();
        int wave = t >> 6, l = t & 63;
        int n_in = l & 15, kc = l >> 4;
        for (int p = 0; p < 4; ++p) {
            int nt = wave * 4 + p;
            int n = nt * 16 + n_in;
            short8 hi, lo;
            #pragma unroll
            for (int j = 0; j < 8; ++j) {
                float x = tile[(kc * 8 + j) * 261 + n];
                short hs = f32_to_bf16(x);
                hi[j] = hs;
                lo[j] = f32_to_bf16(x - bf16_to_f32(hs));
            }
            size_t base = (((size_t)(b * 32 + kt) * 16 + nt) * 512) + (size_t)l * 8;
            *(short8*)(Vhi + base) = hi;
            *(short8*)(Vlo + base) = lo;
        }
    }
}

// score(q,k) = W_sum - 2*sum_h w_h/(Eq_h*Ek_h+1); W_sum cancels in softmax.
// Bounded scores -> no max-subtraction; p = exp(-2s) fused into score phase.
// R13 = R11 + 2-way q-interleave with split accumulators in the score loop:
// two independent q-chains x two partial sums each = 4 independent fma chains
// (R11's single chain left VALUBusy at 47%); shared e/w4 operands.
__global__ __launch_bounds__(1024, 4) void attn_kernel(const float* __restrict__ Eq,
                                                       const float* __restrict__ Ekt,
                                                       const short* __restrict__ Vhi,
                                                       const short* __restrict__ Vlo,
                                                       const float* __restrict__ wv,
                                                       float* __restrict__ out) {
    __shared__ __align__(16) unsigned sc[TQ * 1028];   // 65.8 KB: P hi/lo shorts
    __shared__ float wsum[16 * TQ];
    __shared__ float rinv_s[TQ];

    int tid = threadIdx.x;
    int blk = blockIdx.x;
    // XCD swizzle: blk%8 = XCD; batch b pinned to XCDs {2b,2b+1}.
    int b = (blk & 7) >> 1;
    int tile = (blk >> 3) * 2 + (blk & 1);   // 0..63, bijective per batch
    int qbase = tile * TQ;

    // ---- score phase: thread owns k = tid; q-pairs interleaved ----
    const float* kb = Ekt + (size_t)b * Hh * Kn;
    const float* qp = Eq + (size_t)(b * Qn + qbase) * Hh;
    const float4* wv4 = (const float4*)wv;
    float s[TQ];
    #pragma unroll
    for (int q = 0; q < TQ; ++q) s[q] = 0.f;

    float e0 = kb[0 * Kn + tid];
    float e1 = kb[1 * Kn + tid];
    float e2 = kb[2 * Kn + tid];
    float e3 = kb[3 * Kn + tid];
    for (int h4 = 0; h4 < Hh / 4; ++h4) {
        float n0, n1, n2, n3;
        if (h4 < Hh / 4 - 1) {                 // prefetch next iteration
            const float* kn = kb + (h4 + 1) * 4 * Kn;
            n0 = kn[0 * Kn + tid];
            n1 = kn[1 * Kn + tid];
            n2 = kn[2 * Kn + tid];
            n3 = kn[3 * Kn + tid];
        }
        float4 w4 = wv4[h4];                            // uniform -> s_load
        #pragma unroll
        for (int qq = 0; qq < TQ; qq += 2) {            // 2-way q interleave
            float4 qva = *(const float4*)(qp + qq * Hh + h4 * 4);        // s_load
            float4 qvb = *(const float4*)(qp + (qq + 1) * Hh + h4 * 4);  // s_load
            // chain A0
            float aa  = fmaf(qva.x, e0, 1.f);
            float ab  = fmaf(qva.y, e1, 1.f);
            float nab_a = fmaf(w4.x, ab, w4.y * aa);
            // chain B0
            float ba  = fmaf(qvb.x, e0, 1.f);
            float bb  = fmaf(qvb.y, e1, 1.f);
            float nab_b = fmaf(w4.x, bb, w4.y * ba);
            // chain A1
            float ac  = fmaf(qva.z, e2, 1.f);
            float ad  = fmaf(qva.w, e3, 1.f);
            float ncd_a = fmaf(w4.z, ad, w4.w * ac);
            // chain B1
            float bc  = fmaf(qvb.z, e2, 1.f);
            float bd  = fmaf(qvb.w, e3, 1.f);
            float ncd_b = fmaf(w4.z, bd, w4.w * bc);
            float ra0 = __builtin_amdgcn_rcpf(aa * ab);
            float rb0 = __builtin_amdgcn_rcpf(ba * bb);
            float ra1 = __builtin_amdgcn_rcpf(ac * ad);
            float rb1 = __builtin_amdgcn_rcpf(bc * bd);
            s[qq]     = fmaf(nab_a, ra0, s[qq]);
            s[qq + 1] = fmaf(nab_b, rb0, s[qq + 1]);
            s[qq]     = fmaf(ncd_a, ra1, s[qq]);
            s[qq + 1] = fmaf(ncd_b, rb1, s[qq + 1]);
        }
        e0 = n0; e1 = n1; e2 = n2; e3 = n3;
    }

    // p = exp(-2s); write bf16 hi/lo b16; per-q wave partials.
    unsigned short* sp = (unsigned short*)sc;
    float part[TQ];
    #pragma unroll
    for (int q = 0; q < TQ; ++q) {
        float p = __expf(-2.f * s[q]);
        part[q] = p;
        short hs = f32_to_bf16(p);
        sp[q * 2056 + tid] = (unsigned short)hs;
        sp[q * 2056 + 1024 + tid] = (unsigned short)f32_to_bf16(p - bf16_to_f32(hs));
    }

    int wave = tid >> 6, lane = tid & 63;
    #pragma unroll
    for (int q = 0; q < TQ; ++q) {
        #pragma unroll
        for (int off = 32; off >= 1; off >>= 1)
            part[q] += __shfl_xor(part[q], off, 64);
    }
    if (lane == 0) {
        #pragma unroll
        for (int q = 0; q < TQ; ++q) wsum[wave * TQ + q] = part[q];
    }
    __syncthreads();

    {   // wave w finalizes row q=w: sum 16 per-wave partials
        float v = (lane < 16) ? wsum[lane * TQ + wave] : 0.f;
        v += __shfl_xor(v, 8, 64);
        v += __shfl_xor(v, 4, 64);
        v += __shfl_xor(v, 2, 64);
        v += __shfl_xor(v, 1, 64);
        if (lane == 0) rinv_s[wave] = 1.f / v;
    }
    __syncthreads();

    // ---- AV via MFMA: wave owns ntile = wave; all 16 q-cols live ----
    int qf = lane & 15, kc = lane >> 4;
    floatx4 acc = {0.f, 0.f, 0.f, 0.f};
    const char* scb = (const char*)sc;
    for (int kt = 0; kt < 32; ++kt) {
        short8 bhi = *(const short8*)(scb + qf * 4112 + kt * 64 + kc * 16);
        short8 blo = *(const short8*)(scb + qf * 4112 + 2048 + kt * 64 + kc * 16);
        size_t base = (((size_t)(b * 32 + kt) * 16 + wave) * 512) + (size_t)lane * 8;
        short8 ah = *(const short8*)(Vhi + base);
        short8 al = *(const short8*)(Vlo + base);
        acc = __builtin_amdgcn_mfma_f32_16x16x32_bf16(ah, bhi, acc, 0, 0, 0);
        acc = __builtin_amdgcn_mfma_f32_16x16x32_bf16(al, bhi, acc, 0, 0, 0);
        acc = __builtin_amdgcn_mfma_f32_16x16x32_bf16(ah, blo, acc, 0, 0, 0);
    }
    {
        float r = rinv_s[qf];
        float* ob = out + ((size_t)(b * Qn + qbase + qf)) * Dv + wave * 16 + kc * 4;
        float4 o = { acc[0] * r, acc[1] * r, acc[2] * r, acc[3] * r };
        *(float4*)ob = o;
    }
}

extern "C" void kernel_launch(void* const* d_in, const int* in_sizes, int n_in,
                              void* d_out, int out_size, void* d_ws, size_t ws_size,
                              hipStream_t stream) {
    const float* queries = (const float*)d_in[0];
    const float* keys    = (const float*)d_in[1];
    const float* values  = (const float*)d_in[2];
    const float* W_q     = (const float*)d_in[3];
    const float* W_k     = (const float*)d_in[4];
    const float* w_v     = (const float*)d_in[5];
    float* out = (float*)d_out;

    float* Eq  = (float*)d_ws;                 // [B*Q, H]      1 MB
    float* Ekt = Eq + Bn * Qn * Hh;            // [B, H, K]     1 MB
    short* Vhi = (short*)(Ekt + Bn * Kn * Hh); // frag-order    2 MB
    short* Vlo = Vhi + (size_t)Bn * Kn * Dv;   // frag-order    2 MB

    prep_kernel<<<640, 256, 0, stream>>>(queries, W_q, keys, W_k, values,
                                         Eq, Ekt, Vhi, Vlo);
    attn_kernel<<<Bn * (Qn / TQ), 1024, 0, stream>>>(Eq, Ekt, Vhi, Vlo, w_v, out);
}

// Round 15
// 127.920 us; speedup vs baseline: 1.2088x; 1.0124x over previous
//
#include <hip/hip_runtime.h>

#define Bn 4
#define Qn 1024
#define Kn 1024
#define Dd 256
#define Hh 64
#define Dv 256
#define TQ 16

typedef __attribute__((ext_vector_type(8))) short short8;
typedef __attribute__((ext_vector_type(4))) float floatx4;
typedef __attribute__((ext_vector_type(2))) float floatx2;

__device__ __forceinline__ floatx2 fma2(floatx2 a, floatx2 b, floatx2 c) {
    return __builtin_elementwise_fma(a, b, c);
}
__device__ __forceinline__ floatx2 mk2(float x, float y) {
    floatx2 r; r.x = x; r.y = y; return r;
}

__device__ __forceinline__ short f32_to_bf16(float x) {
    unsigned u = __float_as_uint(x);
    unsigned r = u + 0x7fffu + ((u >> 16) & 1u);   // RNE
    return (short)(r >> 16);
}
__device__ __forceinline__ float bf16_to_f32(short h) {
    return __uint_as_float(((unsigned)(unsigned short)h) << 16);
}

// Fused prep (R11/R13 exact, known good):
//  blocks 0..511  : projections (Eq + transposed Ekt, exp-folded), 4 rows/wave
//  blocks 512..639: V -> split-bf16 MFMA-A-fragment swizzle
__global__ __launch_bounds__(256) void prep_kernel(const float* __restrict__ Xq,
                                                   const float* __restrict__ Wq,
                                                   const float* __restrict__ Xk,
                                                   const float* __restrict__ Wk,
                                                   const float* __restrict__ V,
                                                   float* __restrict__ Eq,
                                                   float* __restrict__ Ekt,
                                                   short* __restrict__ Vhi,
                                                   short* __restrict__ Vlo) {
    __shared__ float tile[32 * 261];
    int t = threadIdx.x;
    if (blockIdx.x < 512) {
        int gw = blockIdx.x * 4 + (t >> 6);
        int h = t & 63;
        int side = gw >> 10;
        int row0 = (gw & 1023) * 4;
        const float* X = side ? Xk : Xq;
        const float* W = side ? Wk : Wq;
        float acc[4] = {0.f, 0.f, 0.f, 0.f};
        for (int d4 = 0; d4 < Dd / 4; ++d4) {
            float w0 = W[(d4 * 4 + 0) * Hh + h];
            float w1 = W[(d4 * 4 + 1) * Hh + h];
            float w2 = W[(d4 * 4 + 2) * Hh + h];
            float w3 = W[(d4 * 4 + 3) * Hh + h];
            #pragma unroll
            for (int r = 0; r < 4; ++r) {
                float4 xv = ((const float4*)(X + (row0 + r) * Dd))[d4];
                acc[r] = fmaf(xv.x, w0, acc[r]);
                acc[r] = fmaf(xv.y, w1, acc[r]);
                acc[r] = fmaf(xv.z, w2, acc[r]);
                acc[r] = fmaf(xv.w, w3, acc[r]);
            }
        }
        #pragma unroll
        for (int r = 0; r < 4; ++r) {
            int row = row0 + r;
            float e = __expf(2.f * acc[r]);
            if (!side) {
                Eq[row * Hh + h] = e;
            } else {
                int b = row >> 10, k = row & 1023;
                Ekt[(b * Hh + h) * Kn + k] = e;
            }
        }
    } else {
        int blk = blockIdx.x - 512;
        int b = blk >> 5;
        int kt = blk & 31;
        const float* Vg = V + (b * Kn + kt * 32) * Dv;
        for (int i = 0; i < 8; ++i) {
            int k = i * 4 + (t >> 6);
            int n4 = (t & 63) * 4;
            float4 v = *(const float4*)(Vg + k * Dv + n4);
            tile[k * 261 + n4 + 0] = v.x;
            tile[k * 261 + n4 + 1] = v.y;
            tile[k * 261 + n4 + 2] = v.z;
            tile[k * 261 + n4 + 3] = v.w;
        }
        __syncthreads();
        int wave = t >> 6, l = t & 63;
        int n_in = l & 15, kc = l >> 4;
        for (int p = 0; p < 4; ++p) {
            int nt = wave * 4 + p;
            int n = nt * 16 + n_in;
            short8 hi, lo;
            #pragma unroll
            for (int j = 0; j < 8; ++j) {
                float x = tile[(kc * 8 + j) * 261 + n];
                short hs = f32_to_bf16(x);
                hi[j] = hs;
                lo[j] = f32_to_bf16(x - bf16_to_f32(hs));
            }
            size_t base = (((size_t)(b * 32 + kt) * 16 + nt) * 512) + (size_t)l * 8;
            *(short8*)(Vhi + base) = hi;
            *(short8*)(Vlo + base) = lo;
        }
    }
}

// score(q,k) = W_sum - 2*sum_h w_h/(Eq_h*Ek_h+1); W_sum cancels in softmax.
// R14b: 4-way rcp grouping (one rcp per 4 h-terms: num/(abcd)) + packed fp32
// (float2 ext-vector chains -> v_pk_fma_f32, 2 FMA/lane/cyc). abcd overflow
// (<=~2e38) is graceful: rcp(inf)=0 exactly where the true contribution ~0.
// Bounded scores -> no max-subtraction; p = exp(-2s) fused into score phase.
__global__ __launch_bounds__(1024, 4) void attn_kernel(const float* __restrict__ Eq,
                                                       const float* __restrict__ Ekt,
                                                       const short* __restrict__ Vhi,
                                                       const short* __restrict__ Vlo,
                                                       const float* __restrict__ wv,
                                                       float* __restrict__ out) {
    __shared__ __align__(16) unsigned sc[TQ * 1028];   // 65.8 KB: P hi/lo shorts
    __shared__ float wsum[16 * TQ];
    __shared__ float rinv_s[TQ];

    int tid = threadIdx.x;
    int blk = blockIdx.x;
    // XCD swizzle: blk%8 = XCD; batch b pinned to XCDs {2b,2b+1}.
    int b = (blk & 7) >> 1;
    int tile = (blk >> 3) * 2 + (blk & 1);   // 0..63, bijective per batch
    int qbase = tile * TQ;

    // ---- score phase: thread owns k = tid; q-pairs packed as float2 ----
    const float* kb = Ekt + (size_t)b * Hh * Kn;
    const float* qp = Eq + (size_t)(b * Qn + qbase) * Hh;
    const float4* wv4 = (const float4*)wv;
    floatx2 s2[TQ / 2];
    #pragma unroll
    for (int i = 0; i < TQ / 2; ++i) { s2[i].x = 0.f; s2[i].y = 0.f; }

    float e0 = kb[0 * Kn + tid];
    float e1 = kb[1 * Kn + tid];
    float e2 = kb[2 * Kn + tid];
    float e3 = kb[3 * Kn + tid];
    floatx2 one2 = mk2(1.f, 1.f);
    for (int h4 = 0; h4 < Hh / 4; ++h4) {
        float n0, n1, n2, n3;
        if (h4 < Hh / 4 - 1) {                 // prefetch next iteration
            const float* kn = kb + (h4 + 1) * 4 * Kn;
            n0 = kn[0 * Kn + tid];
            n1 = kn[1 * Kn + tid];
            n2 = kn[2 * Kn + tid];
            n3 = kn[3 * Kn + tid];
        }
        float4 w4 = wv4[h4];                            // uniform -> s_load
        floatx2 e0s = mk2(e0, e0), e1s = mk2(e1, e1);
        floatx2 e2s = mk2(e2, e2), e3s = mk2(e3, e3);
        floatx2 wx = mk2(w4.x, w4.x), wy = mk2(w4.y, w4.y);
        floatx2 wz = mk2(w4.z, w4.z), ww = mk2(w4.w, w4.w);
        #pragma unroll
        for (int qq = 0; qq < TQ; qq += 2) {
            float4 qva = *(const float4*)(qp + qq * Hh + h4 * 4);        // s_load
            float4 qvb = *(const float4*)(qp + (qq + 1) * Hh + h4 * 4);  // s_load
            floatx2 A = fma2(mk2(qva.x, qvb.x), e0s, one2);
            floatx2 B = fma2(mk2(qva.y, qvb.y), e1s, one2);
            floatx2 C = fma2(mk2(qva.z, qvb.z), e2s, one2);
            floatx2 D = fma2(mk2(qva.w, qvb.w), e3s, one2);
            floatx2 AB = A * B;
            floatx2 CD = C * D;
            floatx2 ABCD = AB * CD;
            floatx2 NAB = fma2(wx, B, wy * A);
            floatx2 NCD = fma2(wz, D, ww * C);
            floatx2 NUM = fma2(NCD, AB, NAB * CD);
            floatx2 R = mk2(__builtin_amdgcn_rcpf(ABCD.x),
                            __builtin_amdgcn_rcpf(ABCD.y));
            s2[qq >> 1] = fma2(NUM, R, s2[qq >> 1]);
        }
        e0 = n0; e1 = n1; e2 = n2; e3 = n3;
    }

    // p = exp(-2s); write bf16 hi/lo b16; per-q wave partials.
    unsigned short* sp = (unsigned short*)sc;
    float part[TQ];
    #pragma unroll
    for (int q = 0; q < TQ; ++q) {
        float sq = (q & 1) ? s2[q >> 1].y : s2[q >> 1].x;
        float p = __expf(-2.f * sq);
        part[q] = p;
        short hs = f32_to_bf16(p);
        sp[q * 2056 + tid] = (unsigned short)hs;
        sp[q * 2056 + 1024 + tid] = (unsigned short)f32_to_bf16(p - bf16_to_f32(hs));
    }

    int wave = tid >> 6, lane = tid & 63;
    #pragma unroll
    for (int q = 0; q < TQ; ++q) {
        #pragma unroll
        for (int off = 32; off >= 1; off >>= 1)
            part[q] += __shfl_xor(part[q], off, 64);
    }
    if (lane == 0) {
        #pragma unroll
        for (int q = 0; q < TQ; ++q) wsum[wave * TQ + q] = part[q];
    }
    __syncthreads();

    {   // wave w finalizes row q=w: sum 16 per-wave partials
        float v = (lane < 16) ? wsum[lane * TQ + wave] : 0.f;
        v += __shfl_xor(v, 8, 64);
        v += __shfl_xor(v, 4, 64);
        v += __shfl_xor(v, 2, 64);
        v += __shfl_xor(v, 1, 64);
        if (lane == 0) rinv_s[wave] = 1.f / v;
    }
    __syncthreads();

    // ---- AV via MFMA: wave owns ntile = wave; all 16 q-cols live ----
    int qf = lane & 15, kc = lane >> 4;
    floatx4 acc = {0.f, 0.f, 0.f, 0.f};
    const char* scb = (const char*)sc;
    for (int kt = 0; kt < 32; ++kt) {
        short8 bhi = *(const short8*)(scb + qf * 4112 + kt * 64 + kc * 16);
        short8 blo = *(const short8*)(scb + qf * 4112 + 2048 + kt * 64 + kc * 16);
        size_t base = (((size_t)(b * 32 + kt) * 16 + wave) * 512) + (size_t)lane * 8;
        short8 ah = *(const short8*)(Vhi + base);
        short8 al = *(const short8*)(Vlo + base);
        acc = __builtin_amdgcn_mfma_f32_16x16x32_bf16(ah, bhi, acc, 0, 0, 0);
        acc = __builtin_amdgcn_mfma_f32_16x16x32_bf16(al, bhi, acc, 0, 0, 0);
        acc = __builtin_amdgcn_mfma_f32_16x16x32_bf16(ah, blo, acc, 0, 0, 0);
    }
    {
        float r = rinv_s[qf];
        float* ob = out + ((size_t)(b * Qn + qbase + qf)) * Dv + wave * 16 + kc * 4;
        float4 o = { acc[0] * r, acc[1] * r, acc[2] * r, acc[3] * r };
        *(float4*)ob = o;
    }
}

extern "C" void kernel_launch(void* const* d_in, const int* in_sizes, int n_in,
                              void* d_out, int out_size, void* d_ws, size_t ws_size,
                              hipStream_t stream) {
    const float* queries = (const float*)d_in[0];
    const float* keys    = (const float*)d_in[1];
    const float* values  = (const float*)d_in[2];
    const float* W_q     = (const float*)d_in[3];
    const float* W_k     = (const float*)d_in[4];
    const float* w_v     = (const float*)d_in[5];
    float* out = (float*)d_out;

    float* Eq  = (float*)d_ws;                 // [B*Q, H]      1 MB
    float* Ekt = Eq + Bn * Qn * Hh;            // [B, H, K]     1 MB
    short* Vhi = (short*)(Ekt + Bn * Kn * Hh); // frag-order    2 MB
    short* Vlo = Vhi + (size_t)Bn * Kn * Dv;   // frag-order    2 MB

    prep_kernel<<<640, 256, 0, stream>>>(queries, W_q, keys, W_k, values,
                                         Eq, Ekt, Vhi, Vlo);
    attn_kernel<<<Bn * (Qn / TQ), 1024, 0, stream>>>(Eq, Ekt, Vhi, Vlo, w_v, out);
}